// Round 10
// baseline (163.136 us; speedup 1.0000x reference)
//
#include <hip/hip_runtime.h>
#include <hip/hip_bf16.h>

// B=2, S=2048, E=1024, H=16, D=64. f32 in/out; bf16 MFMA internally.
// R9: barrier-free attention — K/V fragments loaded DIRECTLY from global (L2-resident
//     via bh->XCD swizzle; LDS staging was pure overhead per Common-mistake #7).
//     No __syncthreads in attn at all; per-wave P buffer only; K reg-prefetch (unroll x2).
//     Split-K reverted (atomics regressed R8).

typedef __bf16 bf16;
typedef __bf16 bf16x4 __attribute__((ext_vector_type(4)));
typedef __bf16 bf16x8 __attribute__((ext_vector_type(8)));
typedef float  f32x4  __attribute__((ext_vector_type(4)));

#define MNEG (-1.0e30f)
#define QSCALE 0.1803368801f   // 0.125 * log2(e): folded into Q at GEMM1 epilogue

__device__ __forceinline__ void gload16(const bf16* g, bf16* l) {
  __builtin_amdgcn_global_load_lds((const __attribute__((address_space(1))) void*)g,
                                   (__attribute__((address_space(3))) void*)l, 16, 0, 0);
}

// ---------------- fused prep: x cvt (blocks 0..2047), W_attn^T, W_proj^T ----------------
__global__ __launch_bounds__(256) void prep_k(const float* __restrict__ x, bf16* __restrict__ xb,
                                              const float* __restrict__ Wa, bf16* __restrict__ WaT,
                                              const float* __restrict__ Wp, bf16* __restrict__ WpT) {
  const int bid = blockIdx.x;
  if (bid < 2048) {
    const int i = bid * 256 + threadIdx.x;
    f32x4 a = ((const f32x4*)x)[2 * i], b = ((const f32x4*)x)[2 * i + 1];
    bf16x8 o;
    for (int j = 0; j < 4; ++j) { o[j] = (bf16)a[j]; o[4 + j] = (bf16)b[j]; }
    ((bf16x8*)xb)[i] = o;
    return;
  }
  __shared__ bf16 t[64][68];
  const float* in; bf16* out; int C, cx, cy;
  if (bid < 2816) { in = Wa; out = WaT; C = 3072; const int tt = bid - 2048; cx = tt % 48; cy = tt / 48; }
  else            { in = Wp; out = WpT; C = 1024; const int tt = bid - 2816; cx = tt % 16; cy = tt / 16; }
  const int R = 1024;
  const int c0 = cx * 64, r0 = cy * 64;
  const int lr = threadIdx.x >> 4;
  const int lc = (threadIdx.x & 15) * 4;
  for (int i = 0; i < 4; ++i) {
    int r = lr + i * 16;
    f32x4 v = *(const f32x4*)(in + (size_t)(r0 + r) * C + c0 + lc);
    bf16x4 b;
    for (int j = 0; j < 4; ++j) b[j] = (bf16)v[j];
    *(bf16x4*)&t[r][lc] = b;
  }
  __syncthreads();
  for (int i = 0; i < 4; ++i) {
    int c = lr + i * 16;
    bf16x4 v;
    for (int j = 0; j < 4; ++j) v[j] = t[lc + j][c];
    *(bf16x4*)(out + (size_t)(c0 + c) * R + r0 + lc) = v;
  }
}

// ---------------- GEMM: C[M,N] = A[M,K]*Bt[N,K]^T + bias (bf16 in, f32 acc) ----------------
template <int MODE, int BN>
__global__ __launch_bounds__(256) void gemm_bt(const bf16* __restrict__ A,
                                               const bf16* __restrict__ Bt,
                                               const float* __restrict__ bias,
                                               float* __restrict__ C,
                                               bf16* __restrict__ Qo,
                                               bf16* __restrict__ Ko,
                                               bf16* __restrict__ Vo,
                                               int M, int N, int K) {
  constexpr int NT = BN / 32;
  __shared__ bf16 As[128 * 32];
  __shared__ bf16 Bs[BN * 32];
  const int tid = threadIdx.x;
  const int w = tid >> 6, l = tid & 63;
  const int nx = gridDim.x;
  const int nwg = nx * gridDim.y;
  const int flat = blockIdx.y * nx + blockIdx.x;
  const int swz = (flat & 7) * (nwg >> 3) + (flat >> 3);
  const int m0 = (swz / nx) * 128, n0 = (swz % nx) * BN;
  const int wm = w >> 1, wn = w & 1;
  const int fr = l & 15, fg = l >> 4;
  const int srow = l >> 2;
  const int scol = (l & 3) * 8;

  f32x4 acc[4][NT] = {};

  for (int k0 = 0; k0 < K; k0 += 32) {
    __syncthreads();
    for (int c = 0; c < 2; ++c) {
      const int rowA = 32 * w + 16 * c + srow;
      gload16(A + (size_t)(m0 + rowA) * K + k0 + scol, As + (32 * w + 16 * c) * 32);
    }
    for (int c = 0; c < BN / 64; ++c) {
      const int rb = (BN / 64) * 16 * w + 16 * c;
      gload16(Bt + (size_t)(n0 + rb + srow) * K + k0 + scol, Bs + rb * 32);
    }
    __syncthreads();

    bf16x8 af[4], bfv[NT];
    for (int mt = 0; mt < 4; ++mt)
      af[mt] = *(const bf16x8*)(As + (wm * 64 + mt * 16 + fr) * 32 + 8 * fg);
    for (int nt = 0; nt < NT; ++nt)
      bfv[nt] = *(const bf16x8*)(Bs + (wn * (BN / 2) + nt * 16 + fr) * 32 + 8 * fg);
    for (int mt = 0; mt < 4; ++mt)
      for (int nt = 0; nt < NT; ++nt)
        acc[mt][nt] = __builtin_amdgcn_mfma_f32_16x16x32_bf16(af[mt], bfv[nt], acc[mt][nt], 0, 0, 0);
  }

  for (int mt = 0; mt < 4; ++mt) {
    for (int nt = 0; nt < NT; ++nt) {
      const int row0 = m0 + wm * 64 + mt * 16 + 4 * fg;
      const int col = n0 + wn * (BN / 2) + nt * 16 + fr;
      const float bv = bias[col];
      if (MODE == 0) {
        for (int r = 0; r < 4; ++r)
          C[(size_t)(row0 + r) * N + col] = acc[mt][nt][r] + bv;
      } else {
        const int which = col >> 10, h = (col >> 6) & 15, d = col & 63;
        const int b = row0 >> 11, s = row0 & 2047;
        if (which == 2) {
          bf16x4 vv;
          for (int r = 0; r < 4; ++r) vv[r] = (bf16)(acc[mt][nt][r] + bv);
          *(bf16x4*)(Vo + ((size_t)(b * 16 + h) * 64 + d) * 2048 + s) = vv;
        } else if (which == 0) {
          for (int r = 0; r < 4; ++r)
            Qo[((size_t)(b * 16 + h) * 2048 + s + r) * 64 + d] =
                (bf16)((acc[mt][nt][r] + bv) * QSCALE);
        } else {
          for (int r = 0; r < 4; ++r)
            Ko[((size_t)(b * 16 + h) * 2048 + s + r) * 64 + d] = (bf16)(acc[mt][nt][r] + bv);
        }
      }
    }
  }
}

// ---------------- barrier-free flash attention ----------------
// grid 512 x 256thr: bh = 4*(bid&7)+((bid>>3)&3) (KV L2-resident per XCD);
// pair p = bid>>5 -> q-tiles {p, 31-p} (balanced 33 computes). Wave w owns rows
// [q0+16w,+16) of both tiles. K/V fragments read straight from global; K tile
// register-prefetched one step ahead (explicit unroll x2 for static reg sets).
// Swapped QK^T (score col = q, lane-local softmax), no-max exp2 softmax.
__global__ __launch_bounds__(256) void attn_k(const bf16* __restrict__ Qw,
                                              const bf16* __restrict__ Kw,
                                              const bf16* __restrict__ VtG,
                                              bf16* __restrict__ AO) {
  __shared__ bf16 Psa[4 * 16 * 72];
  __shared__ bf16 Psb[4 * 16 * 72];
  const int tid = threadIdx.x, w = tid >> 6, l = tid & 63;
  const int bid = blockIdx.x;
  const int bh = ((bid & 7) << 2) | ((bid >> 3) & 3);
  const int p = bid >> 5;
  const int qa0 = p * 64, qb0 = (31 - p) * 64;
  const int fr = l & 15, fg = l >> 4;
  const size_t base = (size_t)bh * 2048 * 64;
  const int qaw = qa0 + w * 16, qbw = qb0 + w * 16;
  const int qa = qaw + fr, qb = qbw + fr;
  bf16* Pwa = Psa + w * 16 * 72;
  bf16* Pwb = Psb + w * 16 * 72;

  // per-lane global fragment bases (verified identical coords to the old LDS frags)
  const bf16* Kb = Kw + base + (size_t)fr * 64 + 8 * fg;          // + (kt+c*16)*64 (+32)
  const bf16* Vb = VtG + base + (size_t)fr * 2048 + 8 * fg;       // + dt*16*2048 + kt (+32)

  bf16x8 qfa[2], qfb[2];
  for (int t = 0; t < 2; ++t) {
    qfa[t] = *(const bf16x8*)(Qw + base + (size_t)(qaw + fr) * 64 + 32 * t + 8 * fg);
    qfb[t] = *(const bf16x8*)(Qw + base + (size_t)(qbw + fr) * 64 + 32 * t + 8 * fg);
  }

  f32x4 oa[4] = {}, ob[4] = {};
  float la = 0.f, lb = 0.f;
  bf16x8 k0[8], k1[8], vv[8];

  auto load_k = [&](int kt, bf16x8* k) {
    for (int c = 0; c < 4; ++c) {
      const bf16* r = Kb + (size_t)(kt + c * 16) * 64;
      k[c] = *(const bf16x8*)(r);
      k[4 + c] = *(const bf16x8*)(r + 32);
    }
  };
  auto load_v = [&](int kt) {
    for (int dt = 0; dt < 4; ++dt) {
      const bf16* r = Vb + (size_t)(dt * 16) * 2048 + kt;
      vv[2 * dt] = *(const bf16x8*)(r);
      vv[2 * dt + 1] = *(const bf16x8*)(r + 32);
    }
  };
  auto qk = [&](const bf16x8* k, f32x4 (&sa)[4], f32x4 (&sb)[4], bool doA) {
    __builtin_amdgcn_s_setprio(1);
    for (int c = 0; c < 4; ++c) {
      f32x4 z = {};
      z = __builtin_amdgcn_mfma_f32_16x16x32_bf16(k[c], qfb[0], z, 0, 0, 0);
      sb[c] = __builtin_amdgcn_mfma_f32_16x16x32_bf16(k[4 + c], qfb[1], z, 0, 0, 0);
      if (doA) {
        f32x4 y = {};
        y = __builtin_amdgcn_mfma_f32_16x16x32_bf16(k[c], qfa[0], y, 0, 0, 0);
        sa[c] = __builtin_amdgcn_mfma_f32_16x16x32_bf16(k[4 + c], qfa[1], y, 0, 0, 0);
      }
    }
    __builtin_amdgcn_s_setprio(0);
  };
  auto smpv = [&](f32x4 (&sc)[4], bf16* Pw, f32x4 (&oacc)[4], float& lsum,
                  int q, bool need_mask, int kh) {
    float psum = 0.f;
    for (int c = 0; c < 4; ++c) {
      bf16x4 pb;
      for (int r = 0; r < 4; ++r) {
        float s = sc[c][r];
        if (need_mask && (kh + c * 16 + 4 * fg + r > q)) s = MNEG;
        const float pv = __builtin_amdgcn_exp2f(s);
        psum += pv;
        pb[r] = (bf16)pv;
      }
      *(bf16x4*)(Pw + fr * 72 + c * 16 + 4 * fg) = pb;
    }
    psum += __shfl_xor(psum, 16, 64);
    psum += __shfl_xor(psum, 32, 64);
    lsum += psum;
    asm volatile("" ::: "memory");   // keep P writes before P reads (in-wave DS order)
    __builtin_amdgcn_s_setprio(1);
    for (int t = 0; t < 2; ++t) {
      bf16x8 pa = *(const bf16x8*)(Pw + fr * 72 + 32 * t + 8 * fg);
      for (int dt = 0; dt < 4; ++dt)
        oacc[dt] = __builtin_amdgcn_mfma_f32_16x16x32_bf16(pa, vv[2 * dt + t], oacc[dt], 0, 0, 0);
    }
    __builtin_amdgcn_s_setprio(0);
  };

  f32x4 sa[4], sb[4];
  load_k(0, k0);
  int kt = 0;
  while (true) {
    {  // ---- iteration on k0 ----
      const bool doA = (kt <= qa0);
      load_v(kt);
      qk(k0, sa, sb, doA);
      if (kt + 64 <= qb0) load_k(kt + 64, k1);    // prefetch next K tile
      if (doA) smpv(sa, Pwa, oa, la, qa, kt + 63 > qaw, kt);
      smpv(sb, Pwb, ob, lb, qb, kt + 63 > qbw, kt);
      kt += 64;
      if (kt > qb0) break;
    }
    {  // ---- iteration on k1 ----
      const bool doA = (kt <= qa0);
      load_v(kt);
      qk(k1, sa, sb, doA);
      if (kt + 64 <= qb0) load_k(kt + 64, k0);
      if (doA) smpv(sa, Pwa, oa, la, qa, kt + 63 > qaw, kt);
      smpv(sb, Pwb, ob, lb, qb, kt + 63 > qbw, kt);
      kt += 64;
      if (kt > qb0) break;
    }
  }

  const int b = bh >> 4, h = bh & 15;
  auto store = [&](const f32x4 (&oacc)[4], float l2, int qw0) {
    float linv[4];
    for (int r = 0; r < 4; ++r)
      linv[r] = 1.f / __shfl(l2, (l & 48) | (4 * fg + r), 64);
    for (int dt = 0; dt < 4; ++dt)
      for (int r = 0; r < 4; ++r) {
        const int qq = qw0 + 4 * fg + r;
        AO[(size_t)(b * 2048 + qq) * 1024 + h * 64 + dt * 16 + fr] =
            (bf16)(oacc[dt][r] * linv[r]);
      }
  };
  store(oa, la, qaw);
  store(ob, lb, qbw);
}

// ---------------- launch ----------------
extern "C" void kernel_launch(void* const* d_in, const int* in_sizes, int n_in,
                              void* d_out, int out_size, void* d_ws, size_t ws_size,
                              hipStream_t stream) {
  const float* x      = (const float*)d_in[0];
  const float* W_attn = (const float*)d_in[1];
  const float* b_attn = (const float*)d_in[2];
  const float* W_proj = (const float*)d_in[3];
  const float* b_proj = (const float*)d_in[4];
  float* out = (float*)d_out;

  char* ws = (char*)d_ws;
  bf16* WaT = (bf16*)(ws);                 // 6291456 B
  bf16* WpT = (bf16*)(ws + 6291456);       // 2097152 B
  bf16* Qw  = (bf16*)(ws + 8388608);       // [B,H,S,D] (pre-scaled by QSCALE)
  bf16* Kw  = (bf16*)(ws + 16777216);      // [B,H,S,D]
  bf16* VtG = (bf16*)(ws + 25165824);      // [B,H,D,S]
  bf16* AO  = (bf16*)(ws + 33554432);      // [B,S,E] bf16; aliased as xb pre-attn
  bf16* xb  = AO;

  prep_k<<<3072, 256, 0, stream>>>(x, xb, W_attn, WaT, W_proj, WpT);

  gemm_bt<1, 128><<<dim3(24, 32), 256, 0, stream>>>(
      xb, WaT, b_attn, nullptr, Qw, Kw, VtG, 4096, 3072, 1024);

  attn_k<<<512, 256, 0, stream>>>(Qw, Kw, VtG, AO);

  gemm_bt<0, 64><<<dim3(16, 32), 256, 0, stream>>>(
      AO, WpT, b_proj, out, nullptr, nullptr, nullptr, 4096, 1024, 1024);
}

// Round 11
// 115.077 us; speedup vs baseline: 1.4176x; 1.4176x over previous
//
#include <hip/hip_runtime.h>
#include <hip/hip_bf16.h>

// B=2, S=2048, E=1024, H=16, D=64. f32 in/out; bf16 MFMA internally.
// R10: attn -> one 64-row q-tile per block, grid 1024, heavy-first dispatch,
//      3 blocks/CU (LDS 45KB, launch_bounds(256,3)). KVBLK=128, T14 prefetch,
//      no-max exp2 softmax, setprio, XCD-bh map. GEMMs/prep unchanged (R7).

typedef __bf16 bf16;
typedef __bf16 bf16x4 __attribute__((ext_vector_type(4)));
typedef __bf16 bf16x8 __attribute__((ext_vector_type(8)));
typedef float  f32x4  __attribute__((ext_vector_type(4)));

#define MNEG (-1.0e30f)
#define QSCALE 0.1803368801f   // 0.125 * log2(e): folded into Q at GEMM1 epilogue

__device__ __forceinline__ void gload16(const bf16* g, bf16* l) {
  __builtin_amdgcn_global_load_lds((const __attribute__((address_space(1))) void*)g,
                                   (__attribute__((address_space(3))) void*)l, 16, 0, 0);
}

// ---------------- fused prep: x cvt (blocks 0..2047), W_attn^T, W_proj^T ----------------
__global__ __launch_bounds__(256) void prep_k(const float* __restrict__ x, bf16* __restrict__ xb,
                                              const float* __restrict__ Wa, bf16* __restrict__ WaT,
                                              const float* __restrict__ Wp, bf16* __restrict__ WpT) {
  const int bid = blockIdx.x;
  if (bid < 2048) {
    const int i = bid * 256 + threadIdx.x;
    f32x4 a = ((const f32x4*)x)[2 * i], b = ((const f32x4*)x)[2 * i + 1];
    bf16x8 o;
    for (int j = 0; j < 4; ++j) { o[j] = (bf16)a[j]; o[4 + j] = (bf16)b[j]; }
    ((bf16x8*)xb)[i] = o;
    return;
  }
  __shared__ bf16 t[64][68];
  const float* in; bf16* out; int C, cx, cy;
  if (bid < 2816) { in = Wa; out = WaT; C = 3072; const int tt = bid - 2048; cx = tt % 48; cy = tt / 48; }
  else            { in = Wp; out = WpT; C = 1024; const int tt = bid - 2816; cx = tt % 16; cy = tt / 16; }
  const int R = 1024;
  const int c0 = cx * 64, r0 = cy * 64;
  const int lr = threadIdx.x >> 4;
  const int lc = (threadIdx.x & 15) * 4;
  for (int i = 0; i < 4; ++i) {
    int r = lr + i * 16;
    f32x4 v = *(const f32x4*)(in + (size_t)(r0 + r) * C + c0 + lc);
    bf16x4 b;
    for (int j = 0; j < 4; ++j) b[j] = (bf16)v[j];
    *(bf16x4*)&t[r][lc] = b;
  }
  __syncthreads();
  for (int i = 0; i < 4; ++i) {
    int c = lr + i * 16;
    bf16x4 v;
    for (int j = 0; j < 4; ++j) v[j] = t[lc + j][c];
    *(bf16x4*)(out + (size_t)(c0 + c) * R + r0 + lc) = v;
  }
}

// ---------------- GEMM: C[M,N] = A[M,K]*Bt[N,K]^T + bias (bf16 in, f32 acc) ----------------
template <int MODE, int BN>
__global__ __launch_bounds__(256) void gemm_bt(const bf16* __restrict__ A,
                                               const bf16* __restrict__ Bt,
                                               const float* __restrict__ bias,
                                               float* __restrict__ C,
                                               bf16* __restrict__ Qo,
                                               bf16* __restrict__ Ko,
                                               bf16* __restrict__ Vo,
                                               int M, int N, int K) {
  constexpr int NT = BN / 32;
  __shared__ bf16 As[128 * 32];
  __shared__ bf16 Bs[BN * 32];
  const int tid = threadIdx.x;
  const int w = tid >> 6, l = tid & 63;
  const int nx = gridDim.x;
  const int nwg = nx * gridDim.y;
  const int flat = blockIdx.y * nx + blockIdx.x;
  const int swz = (flat & 7) * (nwg >> 3) + (flat >> 3);
  const int m0 = (swz / nx) * 128, n0 = (swz % nx) * BN;
  const int wm = w >> 1, wn = w & 1;
  const int fr = l & 15, fg = l >> 4;
  const int srow = l >> 2;
  const int scol = (l & 3) * 8;

  f32x4 acc[4][NT] = {};

  for (int k0 = 0; k0 < K; k0 += 32) {
    __syncthreads();
    for (int c = 0; c < 2; ++c) {
      const int rowA = 32 * w + 16 * c + srow;
      gload16(A + (size_t)(m0 + rowA) * K + k0 + scol, As + (32 * w + 16 * c) * 32);
    }
    for (int c = 0; c < BN / 64; ++c) {
      const int rb = (BN / 64) * 16 * w + 16 * c;
      gload16(Bt + (size_t)(n0 + rb + srow) * K + k0 + scol, Bs + rb * 32);
    }
    __syncthreads();

    bf16x8 af[4], bfv[NT];
    for (int mt = 0; mt < 4; ++mt)
      af[mt] = *(const bf16x8*)(As + (wm * 64 + mt * 16 + fr) * 32 + 8 * fg);
    for (int nt = 0; nt < NT; ++nt)
      bfv[nt] = *(const bf16x8*)(Bs + (wn * (BN / 2) + nt * 16 + fr) * 32 + 8 * fg);
    for (int mt = 0; mt < 4; ++mt)
      for (int nt = 0; nt < NT; ++nt)
        acc[mt][nt] = __builtin_amdgcn_mfma_f32_16x16x32_bf16(af[mt], bfv[nt], acc[mt][nt], 0, 0, 0);
  }

  for (int mt = 0; mt < 4; ++mt) {
    for (int nt = 0; nt < NT; ++nt) {
      const int row0 = m0 + wm * 64 + mt * 16 + 4 * fg;
      const int col = n0 + wn * (BN / 2) + nt * 16 + fr;
      const float bv = bias[col];
      if (MODE == 0) {
        for (int r = 0; r < 4; ++r)
          C[(size_t)(row0 + r) * N + col] = acc[mt][nt][r] + bv;
      } else {
        const int which = col >> 10, h = (col >> 6) & 15, d = col & 63;
        const int b = row0 >> 11, s = row0 & 2047;
        if (which == 2) {
          bf16x4 vv;
          for (int r = 0; r < 4; ++r) vv[r] = (bf16)(acc[mt][nt][r] + bv);
          *(bf16x4*)(Vo + ((size_t)(b * 16 + h) * 64 + d) * 2048 + s) = vv;
        } else if (which == 0) {
          for (int r = 0; r < 4; ++r)
            Qo[((size_t)(b * 16 + h) * 2048 + s + r) * 64 + d] =
                (bf16)((acc[mt][nt][r] + bv) * QSCALE);
        } else {
          for (int r = 0; r < 4; ++r)
            Ko[((size_t)(b * 16 + h) * 2048 + s + r) * 64 + d] = (bf16)(acc[mt][nt][r] + bv);
        }
      }
    }
  }
}

// ---------------- flash attention: one 64-row q-tile per block, heavy-first ----------------
// grid 1024: bh = 4*(bid&7)+((bid>>3)&3) (XCD spread, KV L2-resident);
// tile qt = 31 - (bid>>5) -> heavy tiles dispatched first (tail minimization).
// KVBLK=128 staged (2 x 64-key compute halves), T14 reg prefetch one round ahead.
// Swapped QK^T (score col = q, lane-local softmax), no-max exp2 softmax.
__global__ __launch_bounds__(256, 3) void attn_k(const bf16* __restrict__ Qw,
                                                 const bf16* __restrict__ Kw,
                                                 const bf16* __restrict__ VtG,
                                                 bf16* __restrict__ AO) {
  __shared__ bf16 Ks[128 * 72];        // K tile [k][d]
  __shared__ bf16 Vt[64 * 136];        // V^T tile [d][k 0..127]
  __shared__ bf16 Ps[4 * 16 * 72];     // per-wave P
  const int tid = threadIdx.x, w = tid >> 6, l = tid & 63;
  const int bid = blockIdx.x;
  const int bh = ((bid & 7) << 2) | ((bid >> 3) & 3);
  const int qt = 31 - (bid >> 5);             // heavy-first
  const int q0 = qt * 64;
  const int fr = l & 15, fg = l >> 4;
  const size_t base = (size_t)bh * 2048 * 64;
  const int qw0 = q0 + w * 16;
  const int q = qw0 + fr;
  bf16* Pw = Ps + w * 16 * 72;
  const int r8 = tid >> 3, c8 = (tid & 7) * 8;      // Ks staging coords
  const int r16 = tid >> 4, c16 = (tid & 15) * 8;   // Vt staging coords

  bf16x8 qf[2];
  for (int t = 0; t < 2; ++t)
    qf[t] = *(const bf16x8*)(Qw + base + (size_t)(qw0 + fr) * 64 + 32 * t + 8 * fg);

  f32x4 oacc[4] = {};
  float lsum = 0.f;
  bf16x8 kreg[4], vreg[4];

  auto load_tile = [&](int kt) {   // 128 keys; tail overshoot stays in ws, never consumed
    for (int c = 0; c < 4; ++c) {
      kreg[c] = *(const bf16x8*)(Kw + base + (size_t)(kt + r8 + 32 * c) * 64 + c8);
      vreg[c] = *(const bf16x8*)(VtG + base + (size_t)(r16 + 16 * c) * 2048 + kt + c16);
    }
  };
  auto write_tile = [&]() {
    for (int c = 0; c < 4; ++c) {
      *(bf16x8*)(Ks + (r8 + 32 * c) * 72 + c8) = kreg[c];
      *(bf16x8*)(Vt + (r16 + 16 * c) * 136 + c16) = vreg[c];
    }
  };

  load_tile(0);
  write_tile();
  __syncthreads();

  for (int kt = 0; kt <= q0; kt += 128) {
    const bool havenext = (kt + 128 <= q0);
    if (havenext) load_tile(kt + 128);      // T14: issue early, hide under compute

    for (int h = 0; h < 2; ++h) {
      const int kh = kt + 64 * h;
      if (kh > q0) break;

      // QK^T: St[k][q], 4 k-subtiles of 16
      f32x4 sc[4];
      __builtin_amdgcn_s_setprio(1);
      for (int c = 0; c < 4; ++c) {
        bf16x8 kf0 = *(const bf16x8*)(Ks + (64 * h + c * 16 + fr) * 72 + 8 * fg);
        bf16x8 kf1 = *(const bf16x8*)(Ks + (64 * h + c * 16 + fr) * 72 + 32 + 8 * fg);
        f32x4 z = {};
        z = __builtin_amdgcn_mfma_f32_16x16x32_bf16(kf0, qf[0], z, 0, 0, 0);
        sc[c] = __builtin_amdgcn_mfma_f32_16x16x32_bf16(kf1, qf[1], z, 0, 0, 0);
      }
      __builtin_amdgcn_s_setprio(0);

      // softmax (no max) -> P, lane-local sum
      const bool need_mask = (kh + 63 > qw0);
      float psum = 0.f;
      for (int c = 0; c < 4; ++c) {
        bf16x4 pb;
        for (int r = 0; r < 4; ++r) {
          float s = sc[c][r];
          if (need_mask && (kh + c * 16 + 4 * fg + r > q)) s = MNEG;
          const float pv = __builtin_amdgcn_exp2f(s);
          psum += pv;
          pb[r] = (bf16)pv;
        }
        *(bf16x4*)(Pw + fr * 72 + c * 16 + 4 * fg) = pb;
      }
      psum += __shfl_xor(psum, 16, 64);
      psum += __shfl_xor(psum, 32, 64);
      lsum += psum;

      asm volatile("" ::: "memory");   // keep P writes before P reads (in-wave DS order)
      __builtin_amdgcn_s_setprio(1);
      for (int t = 0; t < 2; ++t) {
        bf16x8 pa = *(const bf16x8*)(Pw + fr * 72 + 32 * t + 8 * fg);
        for (int dt = 0; dt < 4; ++dt) {
          bf16x8 vf = *(const bf16x8*)(Vt + (dt * 16 + fr) * 136 + 64 * h + 32 * t + 8 * fg);
          oacc[dt] = __builtin_amdgcn_mfma_f32_16x16x32_bf16(pa, vf, oacc[dt], 0, 0, 0);
        }
      }
      __builtin_amdgcn_s_setprio(0);
      asm volatile("" ::: "memory");   // Pw reused next half
    }

    if (!havenext) break;
    __syncthreads();                        // all waves done with Ks/Vt
    write_tile();                           // T14: write-late
    __syncthreads();
  }

  const int b = bh >> 4, h = bh & 15;
  float linv[4];
  for (int r = 0; r < 4; ++r)
    linv[r] = 1.f / __shfl(lsum, (l & 48) | (4 * fg + r), 64);
  for (int dt = 0; dt < 4; ++dt)
    for (int r = 0; r < 4; ++r) {
      const int qq = qw0 + 4 * fg + r;
      AO[(size_t)(b * 2048 + qq) * 1024 + h * 64 + dt * 16 + fr] =
          (bf16)(oacc[dt][r] * linv[r]);
    }
}

// ---------------- launch ----------------
extern "C" void kernel_launch(void* const* d_in, const int* in_sizes, int n_in,
                              void* d_out, int out_size, void* d_ws, size_t ws_size,
                              hipStream_t stream) {
  const float* x      = (const float*)d_in[0];
  const float* W_attn = (const float*)d_in[1];
  const float* b_attn = (const float*)d_in[2];
  const float* W_proj = (const float*)d_in[3];
  const float* b_proj = (const float*)d_in[4];
  float* out = (float*)d_out;

  char* ws = (char*)d_ws;
  bf16* WaT = (bf16*)(ws);                 // 6291456 B
  bf16* WpT = (bf16*)(ws + 6291456);       // 2097152 B
  bf16* Qw  = (bf16*)(ws + 8388608);       // [B,H,S,D] (pre-scaled by QSCALE)
  bf16* Kw  = (bf16*)(ws + 16777216);      // [B,H,S,D]
  bf16* VtG = (bf16*)(ws + 25165824);      // [B,H,D,S]
  bf16* AO  = (bf16*)(ws + 33554432);      // [B,S,E] bf16; aliased as xb pre-attn
  bf16* xb  = AO;

  prep_k<<<3072, 256, 0, stream>>>(x, xb, W_attn, WaT, W_proj, WpT);

  gemm_bt<1, 128><<<dim3(24, 32), 256, 0, stream>>>(
      xb, WaT, b_attn, nullptr, Qw, Kw, VtG, 4096, 3072, 1024);

  attn_k<<<1024, 256, 0, stream>>>(Qw, Kw, VtG, AO);

  gemm_bt<0, 64><<<dim3(16, 32), 256, 0, stream>>>(
      AO, WpT, b_proj, out, nullptr, nullptr, nullptr, 4096, 1024, 1024);
}

// Round 12
// 109.541 us; speedup vs baseline: 1.4893x; 1.0505x over previous
//
#include <hip/hip_runtime.h>
#include <hip/hip_bf16.h>

// B=2, S=2048, E=1024, H=16, D=64. f32 in/out; bf16 MFMA internally.
// R11: GEMMs -> BK=64 via SPLIT LDS arrays (As0/As1, Bs0/Bs1 each 64B-stride,
//      conflict-free, gload_lds-compatible): 16 K-rounds instead of 32, twice the
//      MFMA per barrier pair. attn (R10) and prep unchanged.

typedef __bf16 bf16;
typedef __bf16 bf16x4 __attribute__((ext_vector_type(4)));
typedef __bf16 bf16x8 __attribute__((ext_vector_type(8)));
typedef float  f32x4  __attribute__((ext_vector_type(4)));

#define MNEG (-1.0e30f)
#define QSCALE 0.1803368801f   // 0.125 * log2(e): folded into Q at GEMM1 epilogue

__device__ __forceinline__ void gload16(const bf16* g, bf16* l) {
  __builtin_amdgcn_global_load_lds((const __attribute__((address_space(1))) void*)g,
                                   (__attribute__((address_space(3))) void*)l, 16, 0, 0);
}

// ---------------- fused prep: x cvt (blocks 0..2047), W_attn^T, W_proj^T ----------------
__global__ __launch_bounds__(256) void prep_k(const float* __restrict__ x, bf16* __restrict__ xb,
                                              const float* __restrict__ Wa, bf16* __restrict__ WaT,
                                              const float* __restrict__ Wp, bf16* __restrict__ WpT) {
  const int bid = blockIdx.x;
  if (bid < 2048) {
    const int i = bid * 256 + threadIdx.x;
    f32x4 a = ((const f32x4*)x)[2 * i], b = ((const f32x4*)x)[2 * i + 1];
    bf16x8 o;
    for (int j = 0; j < 4; ++j) { o[j] = (bf16)a[j]; o[4 + j] = (bf16)b[j]; }
    ((bf16x8*)xb)[i] = o;
    return;
  }
  __shared__ bf16 t[64][68];
  const float* in; bf16* out; int C, cx, cy;
  if (bid < 2816) { in = Wa; out = WaT; C = 3072; const int tt = bid - 2048; cx = tt % 48; cy = tt / 48; }
  else            { in = Wp; out = WpT; C = 1024; const int tt = bid - 2816; cx = tt % 16; cy = tt / 16; }
  const int R = 1024;
  const int c0 = cx * 64, r0 = cy * 64;
  const int lr = threadIdx.x >> 4;
  const int lc = (threadIdx.x & 15) * 4;
  for (int i = 0; i < 4; ++i) {
    int r = lr + i * 16;
    f32x4 v = *(const f32x4*)(in + (size_t)(r0 + r) * C + c0 + lc);
    bf16x4 b;
    for (int j = 0; j < 4; ++j) b[j] = (bf16)v[j];
    *(bf16x4*)&t[r][lc] = b;
  }
  __syncthreads();
  for (int i = 0; i < 4; ++i) {
    int c = lr + i * 16;
    bf16x4 v;
    for (int j = 0; j < 4; ++j) v[j] = t[lc + j][c];
    *(bf16x4*)(out + (size_t)(c0 + c) * R + r0 + lc) = v;
  }
}

// ---------------- GEMM: C[M,N] = A[M,K]*Bt[N,K]^T + bias (bf16 in, f32 acc) ----------------
// BK=64 via split arrays (each half keeps 64B row stride: conflict-free, linear for gload_lds).
template <int MODE, int BN>
__global__ __launch_bounds__(256) void gemm_bt(const bf16* __restrict__ A,
                                               const bf16* __restrict__ Bt,
                                               const float* __restrict__ bias,
                                               float* __restrict__ C,
                                               bf16* __restrict__ Qo,
                                               bf16* __restrict__ Ko,
                                               bf16* __restrict__ Vo,
                                               int M, int N, int K) {
  constexpr int NT = BN / 32;
  __shared__ bf16 As0[128 * 32], As1[128 * 32];
  __shared__ bf16 Bs0[BN * 32],  Bs1[BN * 32];
  const int tid = threadIdx.x;
  const int w = tid >> 6, l = tid & 63;
  const int nx = gridDim.x;
  const int nwg = nx * gridDim.y;
  const int flat = blockIdx.y * nx + blockIdx.x;
  const int swz = (flat & 7) * (nwg >> 3) + (flat >> 3);
  const int m0 = (swz / nx) * 128, n0 = (swz % nx) * BN;
  const int wm = w >> 1, wn = w & 1;
  const int fr = l & 15, fg = l >> 4;
  const int srow = l >> 2;          // 0..15
  const int scol = (l & 3) * 8;

  f32x4 acc[4][NT] = {};

  for (int k0 = 0; k0 < K; k0 += 64) {
    __syncthreads();
    for (int c = 0; c < 2; ++c) {
      const int rowA = 32 * w + 16 * c + srow;
      gload16(A + (size_t)(m0 + rowA) * K + k0 + scol,      As0 + (32 * w + 16 * c) * 32);
      gload16(A + (size_t)(m0 + rowA) * K + k0 + 32 + scol, As1 + (32 * w + 16 * c) * 32);
    }
    for (int c = 0; c < BN / 64; ++c) {
      const int rb = (BN / 64) * 16 * w + 16 * c;
      gload16(Bt + (size_t)(n0 + rb + srow) * K + k0 + scol,      Bs0 + rb * 32);
      gload16(Bt + (size_t)(n0 + rb + srow) * K + k0 + 32 + scol, Bs1 + rb * 32);
    }
    __syncthreads();

    bf16x8 af[4][2], bfv[NT][2];
    for (int mt = 0; mt < 4; ++mt) {
      af[mt][0] = *(const bf16x8*)(As0 + (wm * 64 + mt * 16 + fr) * 32 + 8 * fg);
      af[mt][1] = *(const bf16x8*)(As1 + (wm * 64 + mt * 16 + fr) * 32 + 8 * fg);
    }
    for (int nt = 0; nt < NT; ++nt) {
      bfv[nt][0] = *(const bf16x8*)(Bs0 + (wn * (BN / 2) + nt * 16 + fr) * 32 + 8 * fg);
      bfv[nt][1] = *(const bf16x8*)(Bs1 + (wn * (BN / 2) + nt * 16 + fr) * 32 + 8 * fg);
    }
    for (int mt = 0; mt < 4; ++mt)
      for (int nt = 0; nt < NT; ++nt) {
        acc[mt][nt] = __builtin_amdgcn_mfma_f32_16x16x32_bf16(af[mt][0], bfv[nt][0], acc[mt][nt], 0, 0, 0);
        acc[mt][nt] = __builtin_amdgcn_mfma_f32_16x16x32_bf16(af[mt][1], bfv[nt][1], acc[mt][nt], 0, 0, 0);
      }
  }

  for (int mt = 0; mt < 4; ++mt) {
    for (int nt = 0; nt < NT; ++nt) {
      const int row0 = m0 + wm * 64 + mt * 16 + 4 * fg;
      const int col = n0 + wn * (BN / 2) + nt * 16 + fr;
      const float bv = bias[col];
      if (MODE == 0) {
        for (int r = 0; r < 4; ++r)
          C[(size_t)(row0 + r) * N + col] = acc[mt][nt][r] + bv;
      } else {
        const int which = col >> 10, h = (col >> 6) & 15, d = col & 63;
        const int b = row0 >> 11, s = row0 & 2047;
        if (which == 2) {
          bf16x4 vv;
          for (int r = 0; r < 4; ++r) vv[r] = (bf16)(acc[mt][nt][r] + bv);
          *(bf16x4*)(Vo + ((size_t)(b * 16 + h) * 64 + d) * 2048 + s) = vv;
        } else if (which == 0) {
          for (int r = 0; r < 4; ++r)
            Qo[((size_t)(b * 16 + h) * 2048 + s + r) * 64 + d] =
                (bf16)((acc[mt][nt][r] + bv) * QSCALE);
        } else {
          for (int r = 0; r < 4; ++r)
            Ko[((size_t)(b * 16 + h) * 2048 + s + r) * 64 + d] = (bf16)(acc[mt][nt][r] + bv);
        }
      }
    }
  }
}

// ---------------- flash attention: one 64-row q-tile per block, heavy-first (R10) ----------------
__global__ __launch_bounds__(256, 3) void attn_k(const bf16* __restrict__ Qw,
                                                 const bf16* __restrict__ Kw,
                                                 const bf16* __restrict__ VtG,
                                                 bf16* __restrict__ AO) {
  __shared__ bf16 Ks[128 * 72];        // K tile [k][d]
  __shared__ bf16 Vt[64 * 136];        // V^T tile [d][k 0..127]
  __shared__ bf16 Ps[4 * 16 * 72];     // per-wave P
  const int tid = threadIdx.x, w = tid >> 6, l = tid & 63;
  const int bid = blockIdx.x;
  const int bh = ((bid & 7) << 2) | ((bid >> 3) & 3);
  const int qt = 31 - (bid >> 5);             // heavy-first
  const int q0 = qt * 64;
  const int fr = l & 15, fg = l >> 4;
  const size_t base = (size_t)bh * 2048 * 64;
  const int qw0 = q0 + w * 16;
  const int q = qw0 + fr;
  bf16* Pw = Ps + w * 16 * 72;
  const int r8 = tid >> 3, c8 = (tid & 7) * 8;
  const int r16 = tid >> 4, c16 = (tid & 15) * 8;

  bf16x8 qf[2];
  for (int t = 0; t < 2; ++t)
    qf[t] = *(const bf16x8*)(Qw + base + (size_t)(qw0 + fr) * 64 + 32 * t + 8 * fg);

  f32x4 oacc[4] = {};
  float lsum = 0.f;
  bf16x8 kreg[4], vreg[4];

  auto load_tile = [&](int kt) {
    for (int c = 0; c < 4; ++c) {
      kreg[c] = *(const bf16x8*)(Kw + base + (size_t)(kt + r8 + 32 * c) * 64 + c8);
      vreg[c] = *(const bf16x8*)(VtG + base + (size_t)(r16 + 16 * c) * 2048 + kt + c16);
    }
  };
  auto write_tile = [&]() {
    for (int c = 0; c < 4; ++c) {
      *(bf16x8*)(Ks + (r8 + 32 * c) * 72 + c8) = kreg[c];
      *(bf16x8*)(Vt + (r16 + 16 * c) * 136 + c16) = vreg[c];
    }
  };

  load_tile(0);
  write_tile();
  __syncthreads();

  for (int kt = 0; kt <= q0; kt += 128) {
    const bool havenext = (kt + 128 <= q0);
    if (havenext) load_tile(kt + 128);      // T14: issue early

    for (int h = 0; h < 2; ++h) {
      const int kh = kt + 64 * h;
      if (kh > q0) break;

      f32x4 sc[4];
      __builtin_amdgcn_s_setprio(1);
      for (int c = 0; c < 4; ++c) {
        bf16x8 kf0 = *(const bf16x8*)(Ks + (64 * h + c * 16 + fr) * 72 + 8 * fg);
        bf16x8 kf1 = *(const bf16x8*)(Ks + (64 * h + c * 16 + fr) * 72 + 32 + 8 * fg);
        f32x4 z = {};
        z = __builtin_amdgcn_mfma_f32_16x16x32_bf16(kf0, qf[0], z, 0, 0, 0);
        sc[c] = __builtin_amdgcn_mfma_f32_16x16x32_bf16(kf1, qf[1], z, 0, 0, 0);
      }
      __builtin_amdgcn_s_setprio(0);

      const bool need_mask = (kh + 63 > qw0);
      float psum = 0.f;
      for (int c = 0; c < 4; ++c) {
        bf16x4 pb;
        for (int r = 0; r < 4; ++r) {
          float s = sc[c][r];
          if (need_mask && (kh + c * 16 + 4 * fg + r > q)) s = MNEG;
          const float pv = __builtin_amdgcn_exp2f(s);
          psum += pv;
          pb[r] = (bf16)pv;
        }
        *(bf16x4*)(Pw + fr * 72 + c * 16 + 4 * fg) = pb;
      }
      psum += __shfl_xor(psum, 16, 64);
      psum += __shfl_xor(psum, 32, 64);
      lsum += psum;

      asm volatile("" ::: "memory");
      __builtin_amdgcn_s_setprio(1);
      for (int t = 0; t < 2; ++t) {
        bf16x8 pa = *(const bf16x8*)(Pw + fr * 72 + 32 * t + 8 * fg);
        for (int dt = 0; dt < 4; ++dt) {
          bf16x8 vf = *(const bf16x8*)(Vt + (dt * 16 + fr) * 136 + 64 * h + 32 * t + 8 * fg);
          oacc[dt] = __builtin_amdgcn_mfma_f32_16x16x32_bf16(pa, vf, oacc[dt], 0, 0, 0);
        }
      }
      __builtin_amdgcn_s_setprio(0);
      asm volatile("" ::: "memory");
    }

    if (!havenext) break;
    __syncthreads();
    write_tile();                           // T14: write-late
    __syncthreads();
  }

  const int b = bh >> 4, h = bh & 15;
  float linv[4];
  for (int r = 0; r < 4; ++r)
    linv[r] = 1.f / __shfl(lsum, (l & 48) | (4 * fg + r), 64);
  for (int dt = 0; dt < 4; ++dt)
    for (int r = 0; r < 4; ++r) {
      const int qq = qw0 + 4 * fg + r;
      AO[(size_t)(b * 2048 + qq) * 1024 + h * 64 + dt * 16 + fr] =
          (bf16)(oacc[dt][r] * linv[r]);
    }
}

// ---------------- launch ----------------
extern "C" void kernel_launch(void* const* d_in, const int* in_sizes, int n_in,
                              void* d_out, int out_size, void* d_ws, size_t ws_size,
                              hipStream_t stream) {
  const float* x      = (const float*)d_in[0];
  const float* W_attn = (const float*)d_in[1];
  const float* b_attn = (const float*)d_in[2];
  const float* W_proj = (const float*)d_in[3];
  const float* b_proj = (const float*)d_in[4];
  float* out = (float*)d_out;

  char* ws = (char*)d_ws;
  bf16* WaT = (bf16*)(ws);                 // 6291456 B
  bf16* WpT = (bf16*)(ws + 6291456);       // 2097152 B
  bf16* Qw  = (bf16*)(ws + 8388608);       // [B,H,S,D] (pre-scaled by QSCALE)
  bf16* Kw  = (bf16*)(ws + 16777216);      // [B,H,S,D]
  bf16* VtG = (bf16*)(ws + 25165824);      // [B,H,D,S]
  bf16* AO  = (bf16*)(ws + 33554432);      // [B,S,E] bf16; aliased as xb pre-attn
  bf16* xb  = AO;

  prep_k<<<3072, 256, 0, stream>>>(x, xb, W_attn, WaT, W_proj, WpT);

  gemm_bt<1, 128><<<dim3(24, 32), 256, 0, stream>>>(
      xb, WaT, b_attn, nullptr, Qw, Kw, VtG, 4096, 3072, 1024);

  attn_k<<<1024, 256, 0, stream>>>(Qw, Kw, VtG, AO);

  gemm_bt<0, 64><<<dim3(16, 32), 256, 0, stream>>>(
      AO, WpT, b_proj, out, nullptr, nullptr, nullptr, 4096, 1024, 1024);
}